// Round 10
// baseline (317.336 us; speedup 1.0000x reference)
//
#include <hip/hip_runtime.h>

// Problem constants (fixed by reference)
#define CC 32
#define HH 256
#define WW 512
#define NN 4
#define MAXD 48

// Round-10: serial-phase theory test, plain-HIP form (no inline asm).
// Evidence: clean runs R0/R5 (1 stage-drain) 96us, R8 (2/row) 109, R6 (3) 123
// -> time tracks serialized stage->vmcnt(0)drain->compute phases.
// Structure: issue half0 R-DMA (global_load_lds, R7-proven) -> __syncthreads
// (drains HALF the stage, the critical-path cut) -> issue half1 DMA async ->
// compute half0 (half1 lands underneath) -> __syncthreads (~free drain) ->
// compute half1. R5 core geometry throughout: 384 thr, DTILE 8, WTILE 4,
// 2048 blocks, LDS 38912 B, ~80 true VGPR under (384,6) (R5/R8 no-spill).
// Discard criteria: WRITE >> 110 MB or SGPR-report 32 => spill => invalid.
#define WT 256
#define RW (WT + MAXD)    // 304 r columns per half (w0-48 .. w0+255)
#define CH 16             // channels per half
#define DTILE 8           // d per thread; d0 = 8*wid (mult of 4 -> aligned)
#define WTILE 4           // w per thread; wb mult of 4 -> aligned float4
#define NT 384            // 6 waves/block; 64 w-groups x 6 d-groups

__global__ __launch_bounds__(NT, 6)
void cost_volume_kernel(const float* __restrict__ L,
                        const float* __restrict__ R,
                        float* __restrict__ out)
{
    __shared__ float r_s[2][CH][RW];     // 2 x 19456 = 38912 B

    const int t  = threadIdx.x;          // 0..383
    const int w0 = blockIdx.x * WT;      // 0 or 256
    const int h  = blockIdx.y;
    const int n  = blockIdx.z;

    const size_t chw  = (size_t)HH * WW;                       // channel stride
    const size_t rowB = (size_t)n * CC * chw + (size_t)h * WW; // (n, c=0, h, 0)

    const int lane = t & 63;
    const int wid  = t >> 6;             // 0..5, wave-uniform
    const int wb   = lane * WTILE;       // 0..252, multiple of 4
    const int d0   = wid * DTILE;        // 0,8,16,24,32,40
    // r_s col for (local w=wb+i, d=d0+k): wb+i+48-d0-k -> window [wb+41-d0,
    // wb+51-d0]; aligned 12-float superset starts at:
    const int jA = wb + 40 - d0;         // multiple of 4; 0..292, +11 <= 303

    // DMA staging of one half: 1216 float4 slots, slot = c*76 + j4, LDS byte
    // = half*19456 + slot*16 (linear in slot: wave-uniform base + lane*16).
    // Coverage: k=0..3, slot0 = k*384 + wid*64; k=3 only wid=0 (1152..1215).
    // Per-lane g>=0 mask leaves pad holes (R7-proven contract).
#define ISSUE_HALF(half) do {                                                 \
        _Pragma("unroll")                                                     \
        for (int k = 0; k < 4; ++k) {                                         \
            const int slot0 = k * NT + wid * 64;     /* wave-uniform */       \
            if (slot0 < CH * 76) {                   /* uniform branch */     \
                const int idx = slot0 + lane;                                 \
                const int c   = idx / 76;            /* 76 float4 per row */  \
                const int j4  = idx - c * 76;                                 \
                const int g   = w0 - MAXD + 4 * j4;  /* global w */           \
                if (g >= 0) {                        /* pad holes stay */     \
                    const float* gsrc =                                       \
                        R + rowB + (size_t)((half) * CH + c) * chw + g;       \
                    float* ldst = &r_s[0][0][0]                               \
                                  + (size_t)(half) * (CH * RW) + 4 * slot0;   \
                    __builtin_amdgcn_global_load_lds(                         \
                        (const __attribute__((address_space(1))) void*)gsrc,  \
                        (__attribute__((address_space(3))) void*)ldst,        \
                        16, 0, 0);                                            \
                }                                                             \
            }                                                                 \
        }                                                                     \
    } while (0)

    // Zero the w<0 pad once (cols 0..47 of all rows, both halves): 2*16*12 =
    // 384 float4 slots = one per thread. DMA never writes these bytes (g>=0
    // masked) -> no overlap; first __syncthreads (lgkmcnt 0) makes visible.
    if (w0 == 0) {
        int b  = t / 192;
        int r2 = t - b * 192;
        int c  = r2 / 12;
        int j4 = r2 - c * 12;
        *(float4*)&r_s[b][c][4 * j4] = make_float4(0.f, 0.f, 0.f, 0.f);
    }

    // Prime L chain (latency overlaps half0 drain), then issue half0 DMA.
    const float* lp = L + rowB + w0 + wb;     // + c*chw per channel, aligned
    float4 lv0 = *(const float4*)(lp);
    float4 lv1 = *(const float4*)(lp + chw);

    ISSUE_HALF(0);

    __syncthreads();                     // drains HALF the stage (+2 L loads)

    ISSUE_HALF(1);                       // async; lands under half0 compute

    float acc[DTILE][WTILE];
    #pragma unroll
    for (int k = 0; k < DTILE; ++k)
        #pragma unroll
        for (int i = 0; i < WTILE; ++i)
            acc[k][i] = 0.f;

    // ---- half 0 compute (c = 0..15); L prefetch runs ahead into c=16,17
    #pragma unroll 4
    for (int c = 0; c < CH; ++c) {
        float4 lnext = *(const float4*)(lp + (size_t)(c + 2) * chw);
        float rv[12];
        #pragma unroll
        for (int q = 0; q < 3; ++q)
            *(float4*)&rv[4 * q] = *(const float4*)&r_s[0][c][jA + 4 * q];
        #pragma unroll
        for (int k = 0; k < DTILE; ++k) {
            acc[k][0] += lv0.x * rv[8 - k];   // offsets 1..11, compile-time
            acc[k][1] += lv0.y * rv[9 - k];
            acc[k][2] += lv0.z * rv[10 - k];
            acc[k][3] += lv0.w * rv[11 - k];
        }
        lv0 = lv1;
        lv1 = lnext;
    }

    __syncthreads();   // vmcnt(0) ~free: half1 landed under half0 compute

    // ---- half 1 compute (c = 16..31)
    #pragma unroll 4
    for (int cc = 0; cc < CH; ++cc) {
        const int c = CH + cc;
        float4 lnext;
        if (c + 2 < CC)                       // uniform branch
            lnext = *(const float4*)(lp + (size_t)(c + 2) * chw);
        float rv[12];
        #pragma unroll
        for (int q = 0; q < 3; ++q)
            *(float4*)&rv[4 * q] = *(const float4*)&r_s[1][cc][jA + 4 * q];
        #pragma unroll
        for (int k = 0; k < DTILE; ++k) {
            acc[k][0] += lv0.x * rv[8 - k];
            acc[k][1] += lv0.y * rv[9 - k];
            acc[k][2] += lv0.z * rv[10 - k];
            acc[k][3] += lv0.w * rv[11 - k];
        }
        lv0 = lv1;
        lv1 = lnext;
    }

#undef ISSUE_HALF

    const float inv = 1.0f / 32.0f;      // mean over C, exact pow2
    #pragma unroll
    for (int k = 0; k < DTILE; ++k) {
        const int d = d0 + k;
        float4 o = make_float4(acc[k][0] * inv, acc[k][1] * inv,
                               acc[k][2] * inv, acc[k][3] * inv);
        *(float4*)(out + (((size_t)n * MAXD + d) * HH + h) * WW + w0 + wb) = o;
    }
}

extern "C" void kernel_launch(void* const* d_in, const int* in_sizes, int n_in,
                              void* d_out, int out_size, void* d_ws, size_t ws_size,
                              hipStream_t stream) {
    const float* L = (const float*)d_in[0];
    const float* R = (const float*)d_in[1];
    float* out = (float*)d_out;
    // d_in[2] (use_naive) is ignored per reference.
    dim3 grid(WW / WT, HH, NN);          // 2 x 256 x 4 = 2048 blocks
    cost_volume_kernel<<<grid, dim3(NT, 1, 1), 0, stream>>>(L, R, out);
}